// Round 5
// baseline (303.203 us; speedup 1.0000x reference)
//
#include <hip/hip_runtime.h>

#define NUM_FINE 1048576
#define NUM_FEATURES 128
#define NUM_SEG 262144

typedef float f32x4 __attribute__((ext_vector_type(4)));
typedef int   i32x4 __attribute__((ext_vector_type(4)));

// ---- Phase 1: histogram of segment ids (int atomics), 4 ids/thread ----
__global__ void count_kernel(const int* __restrict__ ids, int* __restrict__ cnt) {
    int i = (blockIdx.x * blockDim.x + threadIdx.x) * 4;
    i32x4 a = __builtin_nontemporal_load(reinterpret_cast<const i32x4*>(ids + i));
    atomicAdd(&cnt[a.x], 1);
    atomicAdd(&cnt[a.y], 1);
    atomicAdd(&cnt[a.z], 1);
    atomicAdd(&cnt[a.w], 1);
}

// ---- Phase 2a: per-block exclusive scan (1024 elems/block via int4) ----
__global__ void scan1_kernel(const int* __restrict__ cnt, int* __restrict__ base,
                             int* __restrict__ blockSums) {
    __shared__ int lds[256];
    int tid = threadIdx.x;
    int g = blockIdx.x * 1024 + tid * 4;
    int4 a = *reinterpret_cast<const int4*>(cnt + g);
    int s = a.x + a.y + a.z + a.w;
    lds[tid] = s;
    __syncthreads();
    for (int off = 1; off < 256; off <<= 1) {
        int v = (tid >= off) ? lds[tid - off] : 0;
        __syncthreads();
        lds[tid] += v;
        __syncthreads();
    }
    int excl = lds[tid] - s;
    int4 o;
    o.x = excl;
    o.y = o.x + a.x;
    o.z = o.y + a.y;
    o.w = o.z + a.z;
    *reinterpret_cast<int4*>(base + g) = o;
    if (tid == 255) blockSums[blockIdx.x] = lds[255];
}

// ---- Phase 2b (fused): each block re-scans the 256 block sums in LDS,
// picks its own exclusive prefix, and adds it to its 1024 base entries. ----
__global__ void scan3_kernel(int* __restrict__ base, const int* __restrict__ blockSums) {
    __shared__ int lds[256];
    int tid = threadIdx.x;
    int v = blockSums[tid];
    lds[tid] = v;
    __syncthreads();
    for (int off = 1; off < 256; off <<= 1) {
        int t = (tid >= off) ? lds[tid - off] : 0;
        __syncthreads();
        lds[tid] += t;
        __syncthreads();
    }
    int add = (blockIdx.x > 0) ? lds[blockIdx.x - 1] : 0;  // LDS broadcast
    int g = blockIdx.x * 1024 + tid * 4;
    int4 a = *reinterpret_cast<int4*>(base + g);
    a.x += add; a.y += add; a.z += add; a.w += add;
    *reinterpret_cast<int4*>(base + g) = a;
}

// ---- Phase 3: placement, 4 ids/thread. Mutates base[s] -> segment END. ----
__global__ void place_kernel(const int* __restrict__ ids, int* __restrict__ base,
                             int* __restrict__ perm) {
    int i = (blockIdx.x * blockDim.x + threadIdx.x) * 4;
    i32x4 a = __builtin_nontemporal_load(reinterpret_cast<const i32x4*>(ids + i));
    perm[atomicAdd(&base[a.x], 1)] = i;
    perm[atomicAdd(&base[a.y], 1)] = i + 1;
    perm[atomicAdd(&base[a.z], 1)] = i + 2;
    perm[atomicAdd(&base[a.w], 1)] = i + 3;
}

// ---- Phase 4: gather. One wave per segment; lane holds float4 (32 lanes/row,
// 2 rows per load instruction), 4-deep unroll = up to 8 rows in flight.
// Predicated (exec-masked) loads: no duplicate requests. x-loads and out-stores
// are nontemporal (zero reuse -> bypass L1 miss tracking). ----
__global__ void gather_kernel(const float* __restrict__ x,
                              const int* __restrict__ perm,
                              const int* __restrict__ endArr,
                              const int* __restrict__ cnt,
                              float* __restrict__ out) {
    int wid = (blockIdx.x << 2) | (threadIdx.x >> 6);  // segment id
    int lane = threadIdx.x & 63;
    int h = lane >> 5;           // which row of the pair this half-wave reads
    int f = (lane & 31) << 2;    // feature offset (float4)
    int end = endArr[wid];
    int c = cnt[wid];
    f32x4 acc = {0.f, 0.f, 0.f, 0.f};
    for (int r = end - c; r < end; r += 8) {
#pragma unroll
        for (int k = 0; k < 4; ++k) {
            int j = r + (k << 1) + h;
            if (j < end) {                       // half-wave-uniform predication
                int row = perm[j];
                f32x4 v = __builtin_nontemporal_load(
                    reinterpret_cast<const f32x4*>(x + (size_t)row * NUM_FEATURES + f));
                acc += v;
            }
        }
    }
    // combine even-row (h=0) and odd-row (h=1) partials across the halves
    acc.x += __shfl_xor(acc.x, 32);
    acc.y += __shfl_xor(acc.y, 32);
    acc.z += __shfl_xor(acc.z, 32);
    acc.w += __shfl_xor(acc.w, 32);
    if (h == 0) {
        float inv = 1.0f / (float)(c > 1 ? c : 1);   // c==0 -> acc==0 -> writes 0
        f32x4 o = acc * inv;
        __builtin_nontemporal_store(
            o, reinterpret_cast<f32x4*>(out + (size_t)wid * NUM_FEATURES + f));
    }
}

extern "C" void kernel_launch(void* const* d_in, const int* in_sizes, int n_in,
                              void* d_out, int out_size, void* d_ws, size_t ws_size,
                              hipStream_t stream) {
    const float* x   = (const float*)d_in[0];
    const int*   ids = (const int*)d_in[1];
    float* out = (float*)d_out;

    char* ws = (char*)d_ws;
    int* cnt       = (int*)(ws);                        // 1 MiB
    int* base      = (int*)(ws + (1 << 20));            // 1 MiB
    int* blockSums = (int*)(ws + (2 << 20));            // 1 KiB
    int* perm      = (int*)(ws + (3 << 20));            // 4 MiB

    hipMemsetAsync(cnt, 0, (size_t)NUM_SEG * sizeof(int), stream);

    count_kernel<<<NUM_FINE / 1024, 256, 0, stream>>>(ids, cnt);
    scan1_kernel<<<NUM_SEG / 1024, 256, 0, stream>>>(cnt, base, blockSums);
    scan3_kernel<<<NUM_SEG / 1024, 256, 0, stream>>>(base, blockSums);
    place_kernel<<<NUM_FINE / 1024, 256, 0, stream>>>(ids, base, perm);

    // 1 wave per segment, 4 waves per block
    gather_kernel<<<NUM_SEG / 4, 256, 0, stream>>>(x, perm, base, cnt, out);
}

// Round 6
// 209.774 us; speedup vs baseline: 1.4454x; 1.4454x over previous
//
#include <hip/hip_runtime.h>

#define NUM_FINE 1048576
#define NF 128
#define NUM_SEG 262144

typedef float f32x4 __attribute__((ext_vector_type(4)));

// ---- Phase 1: histogram + within-segment rank (fuses place's atomics) ----
__global__ void count_rank_kernel(const int* __restrict__ ids, int* __restrict__ cnt,
                                  int* __restrict__ rank) {
    int i = (blockIdx.x * blockDim.x + threadIdx.x) * 4;
    int4 a = *reinterpret_cast<const int4*>(ids + i);
    int4 r;
    r.x = atomicAdd(&cnt[a.x], 1);
    r.y = atomicAdd(&cnt[a.y], 1);
    r.z = atomicAdd(&cnt[a.z], 1);
    r.w = atomicAdd(&cnt[a.w], 1);
    *reinterpret_cast<int4*>(rank + i) = r;
}

// ---- Phase 2a: per-block exclusive scan (1024 elems/block via int4) ----
__global__ void scan1_kernel(const int* __restrict__ cnt, int* __restrict__ base,
                             int* __restrict__ blockSums) {
    __shared__ int lds[256];
    int tid = threadIdx.x;
    int g = blockIdx.x * 1024 + tid * 4;
    int4 a = *reinterpret_cast<const int4*>(cnt + g);
    int s = a.x + a.y + a.z + a.w;
    lds[tid] = s;
    __syncthreads();
    for (int off = 1; off < 256; off <<= 1) {
        int v = (tid >= off) ? lds[tid - off] : 0;
        __syncthreads();
        lds[tid] += v;
        __syncthreads();
    }
    int excl = lds[tid] - s;
    int4 o;
    o.x = excl;
    o.y = o.x + a.x;
    o.z = o.y + a.y;
    o.w = o.z + a.z;
    *reinterpret_cast<int4*>(base + g) = o;
    if (tid == 255) blockSums[blockIdx.x] = lds[255];
}

// ---- Phase 2b: re-scan block sums in LDS, finalize base, emit (start,cnt) desc ----
__global__ void scan3_kernel(int* __restrict__ base, const int* __restrict__ blockSums,
                             const int* __restrict__ cnt, int2* __restrict__ desc) {
    __shared__ int lds[256];
    int tid = threadIdx.x;
    int v = blockSums[tid];
    lds[tid] = v;
    __syncthreads();
    for (int off = 1; off < 256; off <<= 1) {
        int t = (tid >= off) ? lds[tid - off] : 0;
        __syncthreads();
        lds[tid] += t;
        __syncthreads();
    }
    int add = (blockIdx.x > 0) ? lds[blockIdx.x - 1] : 0;  // LDS broadcast
    int g = blockIdx.x * 1024 + tid * 4;
    int4 b = *reinterpret_cast<int4*>(base + g);
    int4 cc = *reinterpret_cast<const int4*>(cnt + g);
    b.x += add; b.y += add; b.z += add; b.w += add;
    *reinterpret_cast<int4*>(base + g) = b;
    *reinterpret_cast<int4*>(desc + g)     = make_int4(b.x, cc.x, b.y, cc.y);
    *reinterpret_cast<int4*>(desc + g + 2) = make_int4(b.z, cc.z, b.w, cc.w);
}

// ---- Phase 3: placement, atomic-free (rank precomputed) ----
__global__ void place_kernel(const int* __restrict__ ids, const int* __restrict__ base,
                             const int* __restrict__ rank, int* __restrict__ perm) {
    int i = (blockIdx.x * blockDim.x + threadIdx.x) * 4;
    int4 a = *reinterpret_cast<const int4*>(ids + i);
    int4 r = *reinterpret_cast<const int4*>(rank + i);
    perm[base[a.x] + r.x] = i;
    perm[base[a.y] + r.y] = i + 1;
    perm[base[a.z] + r.z] = i + 2;
    perm[base[a.w] + r.w] = i + 3;
}

// One clamped, masked row-pair load: unconditional (keeps MLP), dup-free by caller.
__device__ __forceinline__ f32x4 rowld(const float* __restrict__ x,
                                       const int* __restrict__ perm,
                                       int j, int end, int last, int f) {
    int jj = (j < end) ? j : last;     // clamp -> L1-hit duplicate at worst
    int row = perm[jj];
    f32x4 v = *reinterpret_cast<const f32x4*>(x + (size_t)row * NF + f);
    float m = (j < end) ? 1.f : 0.f;
    return v * m;
}

// ---- Phase 4: gather. One wave per segment; lane holds float4 (2 rows per
// load instr). Wave-uniform case ladder sizes the issued batch to c:
// avg issued rows 8.2 -> 5.1 while every case keeps its loads unconditional. ----
__global__ void gather_kernel(const float* __restrict__ x,
                              const int* __restrict__ perm,
                              const int2* __restrict__ desc,
                              float* __restrict__ out) {
    int wid = (blockIdx.x << 2) | (threadIdx.x >> 6);  // segment id
    int lane = threadIdx.x & 63;
    int h = lane >> 5;           // which row of the pair this half-wave reads
    int f = (lane & 31) << 2;    // feature offset (float4)
    int2 d = desc[wid];
    int start = d.x, c = d.y;
    int end = start + c, last = end - 1;
    f32x4 acc = {0.f, 0.f, 0.f, 0.f};
    if (c > 0) {
        if (c <= 2) {
            acc = rowld(x, perm, start + h, end, last, f);
        } else if (c <= 4) {
            acc = rowld(x, perm, start + h,     end, last, f)
                + rowld(x, perm, start + 2 + h, end, last, f);
        } else if (c <= 8) {
            acc = rowld(x, perm, start + h,     end, last, f)
                + rowld(x, perm, start + 2 + h, end, last, f)
                + rowld(x, perm, start + 4 + h, end, last, f)
                + rowld(x, perm, start + 6 + h, end, last, f);
        } else {
            for (int r = start; r < end; r += 8) {
                acc += rowld(x, perm, r + h,     end, last, f)
                     + rowld(x, perm, r + 2 + h, end, last, f)
                     + rowld(x, perm, r + 4 + h, end, last, f)
                     + rowld(x, perm, r + 6 + h, end, last, f);
            }
        }
        acc.x += __shfl_xor(acc.x, 32);
        acc.y += __shfl_xor(acc.y, 32);
        acc.z += __shfl_xor(acc.z, 32);
        acc.w += __shfl_xor(acc.w, 32);
    }
    if (h == 0) {
        float inv = 1.0f / (float)(c > 1 ? c : 1);   // c==0 -> acc==0 -> writes 0
        f32x4 o = acc * inv;
        *reinterpret_cast<f32x4*>(out + (size_t)wid * NF + f) = o;
    }
}

extern "C" void kernel_launch(void* const* d_in, const int* in_sizes, int n_in,
                              void* d_out, int out_size, void* d_ws, size_t ws_size,
                              hipStream_t stream) {
    const float* x   = (const float*)d_in[0];
    const int*   ids = (const int*)d_in[1];
    float* out = (float*)d_out;

    char* ws = (char*)d_ws;
    int*  cnt       = (int*)(ws);                       // 1 MiB
    int*  base      = (int*)(ws + (1 << 20));           // 1 MiB
    int*  blockSums = (int*)(ws + (2 << 20));           // 1 KiB
    int*  perm      = (int*)(ws + (3 << 20));           // 4 MiB
    int*  rank      = (int*)(ws + (7 << 20));           // 4 MiB
    int2* desc      = (int2*)(ws + (11 << 20));         // 2 MiB

    hipMemsetAsync(cnt, 0, (size_t)NUM_SEG * sizeof(int), stream);

    count_rank_kernel<<<NUM_FINE / 1024, 256, 0, stream>>>(ids, cnt, rank);
    scan1_kernel<<<NUM_SEG / 1024, 256, 0, stream>>>(cnt, base, blockSums);
    scan3_kernel<<<NUM_SEG / 1024, 256, 0, stream>>>(base, blockSums, cnt, desc);
    place_kernel<<<NUM_FINE / 1024, 256, 0, stream>>>(ids, base, rank, perm);

    // 1 wave per segment, 4 waves per block
    gather_kernel<<<NUM_SEG / 4, 256, 0, stream>>>(x, perm, desc, out);
}